// Round 9
// baseline (877.541 us; speedup 1.0000x reference)
//
#include <hip/hip_runtime.h>
#include <hip/hip_fp16.h>
#include <stdint.h>
#include <string.h>

// LightGCN propagation — fp16 pipeline, bucket-direct SpMM (no ELL).
//  K1: LDS-staged counting sort into 640 per-bucket record arrays (full-line
//      flushes) + sample marking.   [proven in R8]
//  K2: pure fp32->fp16 table conversion (streaming only).
//  S1..S3: one block per bucket; 235x64 fp32 accumulators in LDS (stride 68
//      to spread banks); stream the bucket's contiguous records, gather
//      xh[col] (16 lanes x half4), ds_add_f32 into LDS; epilogue blends
//      0.2*self + 0.8*sum, writes fp16 coalesced. Masked layers skip gathers
//      per-record. acc/expand/copy ride along as extra blocks.
//  dot: fused layer-3 accum + batched dot.

#define NUM_USERS 100000
#define NUM_ITEMS 50000
#define N_NODES   150000
#define DIM       64
#define N_EDGES   1200000
#define ND        (N_NODES * DIM)
#define NB        4096
#define NSAMP     (2 * NB)

#define NBKT      640               // buckets
#define RPB       235               // rows per bucket (640*235 = 150400)
#define RSTR      68                // LDS accumulator row stride (floats)
#define BCAP      2176              // records per bucket array (mean 1875, +7s)
#define SCAP      11                // K1 LDS staging records per bucket
#define OVF_CAP   512

#define K1_EDGE_BLOCKS 256
#define K1_ROUNDS      5            // ceil(1.2M / (256 blocks * 1024 edges))
#define K1_MARK_BLOCKS 32

// S-kernel block ranges (512 threads/block)
#define S_ACC_BLOCKS   256          // 32 slots/block * 256 = 8192
#define S_EXP_BLOCKS   1024
#define S_CPY_BLOCKS   293          // 293*512 >= N_NODES

// ---- fp16 pack/unpack helpers (compute in fp32) ---------------------------
__device__ __forceinline__ int h2i(__half2 h) { int r; memcpy(&r, &h, 4); return r; }
__device__ __forceinline__ __half2 i2h(int i) { __half2 h; memcpy(&h, &i, 4); return h; }

__device__ __forceinline__ float4 loadh4(const __half* p) {
    int2 v = *(const int2*)p;
    float2 a = __half22float2(i2h(v.x));
    float2 b = __half22float2(i2h(v.y));
    return make_float4(a.x, a.y, b.x, b.y);
}
__device__ __forceinline__ void storeh4(__half* p, float4 v) {
    int2 o;
    o.x = h2i(__floats2half2_rn(v.x, v.y));
    o.y = h2i(__floats2half2_rn(v.z, v.w));
    *(int2*)p = o;
}

// ---------------------------------------------------------------------------
// K1: LDS-staged counting sort (full-line flushes) + mark samples  [from R8]
// ---------------------------------------------------------------------------
__global__ __launch_bounds__(256)
void k1_kernel(const int* __restrict__ erow,
               const int* __restrict__ ecol,
               const float* __restrict__ evalv,
               const int* __restrict__ users,
               const int* __restrict__ items,
               int* __restrict__ gtails,
               int2* __restrict__ barr,
               int4* __restrict__ ovf,
               int* __restrict__ ovf_cnt,
               unsigned char* __restrict__ mask3) {
    __shared__ int2 stage[NBKT * SCAP];   // 56.3 KB
    __shared__ int  scnt[NBKT];           // 2.5 KB
    if (blockIdx.x < K1_EDGE_BLOCKS) {
        for (int k = threadIdx.x; k < NBKT; k += 256) scnt[k] = 0;
        __syncthreads();
        for (int rnd = 0; rnd < K1_ROUNDS; ++rnd) {
            int base = ((rnd * K1_EDGE_BLOCKS + (int)blockIdx.x) * 256
                        + (int)threadIdx.x) * 4;
            if (base < N_EDGES) {
                int4   r4 = *(const int4*)(erow + base);
                int4   c4 = *(const int4*)(ecol + base);
                float4 v4 = *(const float4*)(evalv + base);
                int   rr[4] = {r4.x, r4.y, r4.z, r4.w};
                int   cc[4] = {c4.x, c4.y, c4.z, c4.w};
                float vv[4] = {v4.x, v4.y, v4.z, v4.w};
                #pragma unroll
                for (int u = 0; u < 4; ++u) {
                    int b    = rr[u] / RPB;
                    int rloc = rr[u] - b * RPB;
                    int2 rec = make_int2(cc[u] | (rloc << 18), __float_as_int(vv[u]));
                    int s = atomicAdd(&scnt[b], 1);
                    if (s < SCAP) {
                        stage[b * SCAP + s] = rec;
                    } else {
                        atomicSub(&scnt[b], 1);
                        int gp = atomicAdd(&gtails[b], 1);
                        if (gp < BCAP) barr[(size_t)b * BCAP + gp] = rec;
                        else { int q = atomicAdd(ovf_cnt, 1);
                               if (q < OVF_CAP)
                                   ovf[q] = make_int4(rr[u], cc[u], __float_as_int(vv[u]), 0); }
                    }
                }
            }
            __syncthreads();
            for (int b = threadIdx.x; b < NBKT; b += 256) {
                int c = scnt[b];
                if (c >= 8) {
                    int gp = atomicAdd(&gtails[b], 8);
                    if (gp + 8 <= BCAP) {
                        int2* dst = barr + (size_t)b * BCAP + gp;
                        #pragma unroll
                        for (int i = 0; i < 8; ++i) dst[i] = stage[b * SCAP + i];
                    } else {
                        for (int i = 0; i < 8; ++i) {
                            int2 rc = stage[b * SCAP + i];
                            if (gp + i < BCAP) barr[(size_t)b * BCAP + gp + i] = rc;
                            else { int q = atomicAdd(ovf_cnt, 1);
                                   if (q < OVF_CAP)
                                       ovf[q] = make_int4(b * RPB + (rc.x >> 18),
                                                          rc.x & 0x3FFFF, rc.y, 0); }
                        }
                    }
                    c -= 8;
                    for (int i = 0; i < c; ++i)
                        stage[b * SCAP + i] = stage[b * SCAP + 8 + i];
                    scnt[b] = c;
                }
            }
            __syncthreads();
        }
        for (int b = threadIdx.x; b < NBKT; b += 256) {
            int c = scnt[b];
            if (c > 0) {
                int gp = atomicAdd(&gtails[b], c);
                for (int i = 0; i < c; ++i) {
                    int2 rc = stage[b * SCAP + i];
                    if (gp + i < BCAP) barr[(size_t)b * BCAP + gp + i] = rc;
                    else { int q = atomicAdd(ovf_cnt, 1);
                           if (q < OVF_CAP)
                               ovf[q] = make_int4(b * RPB + (rc.x >> 18),
                                                  rc.x & 0x3FFFF, rc.y, 0); }
                }
            }
        }
    } else {
        int i = ((int)blockIdx.x - K1_EDGE_BLOCKS) * 256 + (int)threadIdx.x;
        if (i < NB)         mask3[users[i]] = 1;
        else if (i < NSAMP) mask3[NUM_USERS + items[i - NB]] = 1;
    }
}

// ---------------------------------------------------------------------------
// K2: pure streaming fp32->fp16 table conversion
// ---------------------------------------------------------------------------
__global__ void cvt_kernel(const float* __restrict__ ue,
                           const float* __restrict__ ie,
                           __half* __restrict__ xh) {
    const int n4  = ND / 4;
    const int nu4 = NUM_USERS * DIM / 4;
    int i = blockIdx.x * blockDim.x + threadIdx.x;
    int stride = gridDim.x * blockDim.x;
    int2* xh4 = (int2*)xh;
    for (; i < n4; i += stride) {
        float4 v = (i < nu4) ? ((const float4*)ue)[i]
                             : ((const float4*)ie)[i - nu4];
        int2 o;
        o.x = h2i(__floats2half2_rn(v.x, v.y));
        o.y = h2i(__floats2half2_rn(v.z, v.w));
        xh4[i] = o;
    }
}

// ---------------------------------------------------------------------------
// S: bucket-direct spmm + blend; ride-alongs: acc, expand (S1), copy (S1)
// ---------------------------------------------------------------------------
template<bool MASKED, bool ACC_STORE>
__global__ __launch_bounds__(512)
void sp_kernel(const int* __restrict__ gtails,
               const int2* __restrict__ barr,
               const __half* __restrict__ xsrc,
               const float* __restrict__ ue,
               const float* __restrict__ ie,
               const unsigned char* __restrict__ mask,
               const int* __restrict__ erow,
               const int* __restrict__ ecol,
               const unsigned char* __restrict__ mask3,
               unsigned char* __restrict__ mask2,
               const int* __restrict__ ovf_cnt,
               const int4* __restrict__ ovf,
               const int* __restrict__ users,
               const int* __restrict__ items,
               float* __restrict__ acc_small,
               __half* __restrict__ xout) {
    __shared__ float facc[RPB * RSTR];   // 62.4 KB -> 2 blocks/CU
    const int group = threadIdx.x >> 4;  // 0..31
    const int t     = threadIdx.x & 15;  // dim quad

    if (blockIdx.x < NBKT) {
        const int bkt   = blockIdx.x;
        const int rbase = bkt * RPB;
        for (int k = threadIdx.x; k < RPB * RSTR; k += 512) facc[k] = 0.f;
        __syncthreads();

        int n = gtails[bkt];
        n = n < BCAP ? n : BCAP;
        const int2* bp = barr + (size_t)bkt * BCAP;

        int e = group;
        for (; e + 32 < n; e += 64) {          // 2 records in flight per group
            int2 rA = bp[e], rB = bp[e + 32];
            int  rlA = rA.x >> 18, rlB = rB.x >> 18;
            bool aA = !MASKED || mask[rbase + rlA];
            bool aB = !MASKED || mask[rbase + rlB];
            float4 xA, xB;
            if (aA) xA = loadh4(xsrc + (size_t)(rA.x & 0x3FFFF) * DIM + t * 4);
            if (aB) xB = loadh4(xsrc + (size_t)(rB.x & 0x3FFFF) * DIM + t * 4);
            if (aA) {
                float v = __int_as_float(rA.y);
                float* f = &facc[rlA * RSTR + t * 4];
                atomicAdd(f + 0, v * xA.x); atomicAdd(f + 1, v * xA.y);
                atomicAdd(f + 2, v * xA.z); atomicAdd(f + 3, v * xA.w);
            }
            if (aB) {
                float v = __int_as_float(rB.y);
                float* f = &facc[rlB * RSTR + t * 4];
                atomicAdd(f + 0, v * xB.x); atomicAdd(f + 1, v * xB.y);
                atomicAdd(f + 2, v * xB.z); atomicAdd(f + 3, v * xB.w);
            }
        }
        if (e < n) {
            int2 rA = bp[e];
            int  rlA = rA.x >> 18;
            if (!MASKED || mask[rbase + rlA]) {
                float4 xA = loadh4(xsrc + (size_t)(rA.x & 0x3FFFF) * DIM + t * 4);
                float v = __int_as_float(rA.y);
                float* f = &facc[rlA * RSTR + t * 4];
                atomicAdd(f + 0, v * xA.x); atomicAdd(f + 1, v * xA.y);
                atomicAdd(f + 2, v * xA.z); atomicAdd(f + 3, v * xA.w);
            }
        }
        // overflow records (normally zero)
        int novf = *ovf_cnt;
        if (novf > 0) {
            novf = novf < OVF_CAP ? novf : OVF_CAP;
            for (int k = group; k < novf; k += 32) {
                int4 o = ovf[k];
                if (o.x >= rbase && o.x < rbase + RPB &&
                    (!MASKED || mask[o.x])) {
                    float4 xv = loadh4(xsrc + (size_t)o.y * DIM + t * 4);
                    float v = __int_as_float(o.z);
                    float* f = &facc[(o.x - rbase) * RSTR + t * 4];
                    atomicAdd(f + 0, v * xv.x); atomicAdd(f + 1, v * xv.y);
                    atomicAdd(f + 2, v * xv.z); atomicAdd(f + 3, v * xv.w);
                }
            }
        }
        __syncthreads();
        // epilogue: out = 0.2*self + 0.8*sum, fp16 coalesced
        for (int idx = threadIdx.x; idx < RPB * 16; idx += 512) {
            int row = idx >> 4, tt = idx & 15;
            int node = rbase + row;
            if (node >= N_NODES) continue;
            if (MASKED && !mask[node]) continue;
            float4 self = loadh4(xsrc + (size_t)node * DIM + tt * 4);
            const float* f = &facc[row * RSTR + tt * 4];
            float4 r;
            r.x = 0.2f * self.x + 0.8f * f[0];
            r.y = 0.2f * self.y + 0.8f * f[1];
            r.z = 0.2f * self.z + 0.8f * f[2];
            r.w = 0.2f * self.w + 0.8f * f[3];
            storeh4(xout + (size_t)node * DIM + tt * 4, r);
        }
    } else if (blockIdx.x < NBKT + S_ACC_BLOCKS) {
        // accum of the INPUT layer at sampled slots (32 slots/block)
        const int s = ((int)blockIdx.x - NBKT) * 32 + group;   // < 8192
        const int node = (s < NB) ? users[s] : (NUM_USERS + items[s - NB]);
        float4* ap = (float4*)(acc_small + (size_t)s * DIM + t * 4);
        if (ACC_STORE) {
            const float* p = (node < NUM_USERS) ? ue + (size_t)node * DIM
                                                : ie + (size_t)(node - NUM_USERS) * DIM;
            *ap = *(const float4*)(p + t * 4);
        } else {
            float4 v = loadh4(xsrc + (size_t)node * DIM + t * 4);
            float4 a = *ap;
            a.x += v.x; a.y += v.y; a.z += v.z; a.w += v.w;
            *ap = a;
        }
    } else if (blockIdx.x < NBKT + S_ACC_BLOCKS + S_EXP_BLOCKS) {
        // S1 only: mask2 |= cols(rows in mask3)
        int i = ((int)blockIdx.x - NBKT - S_ACC_BLOCKS) * 512 + (int)threadIdx.x;
        const int stride = S_EXP_BLOCKS * 512;
        for (; i < N_EDGES; i += stride)
            if (mask3[erow[i]]) mask2[ecol[i]] = 1;
    } else {
        // S1 only: mask2 |= mask3
        int i = ((int)blockIdx.x - NBKT - S_ACC_BLOCKS - S_EXP_BLOCKS) * 512
                + (int)threadIdx.x;
        if (i < N_NODES && mask3[i]) mask2[i] = 1;
    }
}

// ---------------------------------------------------------------------------
// out[b] = dot(acc[b] + e3[u], acc[NB+b] + e3[i]) / 16   (layer-3 accum fused)
// ---------------------------------------------------------------------------
__global__ void dot_kernel(const int* __restrict__ users,
                           const int* __restrict__ items,
                           const float* __restrict__ acc_small,
                           const __half* __restrict__ emb3,
                           float* __restrict__ out) {
    int w = (blockIdx.x * blockDim.x + threadIdx.x) >> 6;
    int lane = threadIdx.x & 63;
    if (w >= NB) return;
    int u  = users[w];
    int it = items[w];
    float au = acc_small[w * DIM + lane]
             + __half2float(emb3[(size_t)u * DIM + lane]);
    float ai = acc_small[(NB + w) * DIM + lane]
             + __half2float(emb3[(size_t)(NUM_USERS + it) * DIM + lane]);
    float p = au * ai;
    #pragma unroll
    for (int o = 32; o > 0; o >>= 1) p += __shfl_down(p, o, 64);
    if (lane == 0) out[w] = p * (1.0f / 16.0f);
}

// ---------------------------------------------------------------------------
extern "C" void kernel_launch(void* const* d_in, const int* in_sizes, int n_in,
                              void* d_out, int out_size, void* d_ws, size_t ws_size,
                              hipStream_t stream) {
    const int*   users = (const int*)  d_in[0];
    const int*   items = (const int*)  d_in[1];
    const int*   erow  = (const int*)  d_in[2];
    const int*   ecol  = (const int*)  d_in[3];
    const float* evalv = (const float*)d_in[4];
    const float* ue    = (const float*)d_in[5];
    const float* ie    = (const float*)d_in[6];
    float* out = (float*)d_out;

    // workspace layout (~71 MB)
    __half* xh        = (__half*)d_ws;                      // ND halves (19.2MB)
    __half* emb_a     = xh + ND;                            // ND halves
    __half* emb_b     = emb_a + ND;                         // ND halves
    float*  acc_small = (float*)(emb_b + ND);               // NSAMP*DIM fp32
    int2*   barr      = (int2*)(acc_small + NSAMP * DIM);   // NBKT*BCAP int2 (11.1MB)
    int*    gtails    = (int*)(barr + (size_t)NBKT * BCAP); // NBKT
    int*    ovf_cnt   = gtails + NBKT;                      // 1
    int4*   ovf       = (int4*)(((uintptr_t)(ovf_cnt + 1) + 15) & ~(uintptr_t)15);
    unsigned char* mask3 = (unsigned char*)(ovf + OVF_CAP); // N_NODES
    unsigned char* mask2 = mask3 + N_NODES;                 // N_NODES

    // zero gtails | ovf_cnt | ovf | mask3 | mask2 (contiguous, ~310 KB)
    size_t zbytes = (size_t)((mask2 + N_NODES) - (unsigned char*)gtails);
    hipMemsetAsync(gtails, 0, zbytes, stream);

    k1_kernel<<<K1_EDGE_BLOCKS + K1_MARK_BLOCKS, 256, 0, stream>>>(
        erow, ecol, evalv, users, items, gtails, barr, ovf, ovf_cnt, mask3);

    cvt_kernel<<<512, 256, 0, stream>>>(ue, ie, xh);

    // S1: layer 1 (unmasked) + acc0(store) + expand + copy
    sp_kernel<false, true>
        <<<NBKT + S_ACC_BLOCKS + S_EXP_BLOCKS + S_CPY_BLOCKS, 512, 0, stream>>>(
        gtails, barr, xh, ue, ie, nullptr, erow, ecol, mask3, mask2,
        ovf_cnt, ovf, users, items, acc_small, emb_a);

    // S2: layer 2 (mask2) + acc1 (from emb_a)
    sp_kernel<true, false><<<NBKT + S_ACC_BLOCKS, 512, 0, stream>>>(
        gtails, barr, emb_a, nullptr, nullptr, mask2, erow, ecol, mask3, mask2,
        ovf_cnt, ovf, users, items, acc_small, emb_b);

    // S3: layer 3 (mask3) + acc2 (from emb_b)
    sp_kernel<true, false><<<NBKT + S_ACC_BLOCKS, 512, 0, stream>>>(
        gtails, barr, emb_b, nullptr, nullptr, mask3, erow, ecol, mask3, mask2,
        ovf_cnt, ovf, users, items, acc_small, emb_a);

    // dot with layer-3 accum fused
    dot_kernel<<<(NB * 64 + 255) / 256, 256, 0, stream>>>(
        users, items, acc_small, emb_a, out);
}

// Round 10
// 214.080 us; speedup vs baseline: 4.0991x; 4.0991x over previous
//
#include <hip/hip_runtime.h>
#include <hip/hip_fp16.h>
#include <stdint.h>
#include <string.h>

// LightGCN propagation — R8 structure (fp16 + LDS-staged counting sort + ELL)
// with cvt fused into K1's free CU slots.
//  K1: 256 edge blocks (LDS staging, full-line flushes; SCAP=9 -> 48.6KB LDS,
//      3 blocks/CU) + mark blocks + fp32->fp16 cvt ride-along (fills the
//      2 spare block slots per CU; K1 edge phase is latency-bound at ~1.2TB/s
//      so the streaming cvt runs concurrently at full rate).
//  K2: per-bucket ELL build in LDS (coalesced writeout) + mask expand/copy.
//  spmm x3: ELL per-row register accumulation, fp16 gathers, 4 rows/wave,
//      4-edge unroll, fused accum of the input layer. (R9's LDS-atomic
//      variant regressed 4x: 76.8M ds_add_f32 + bank conflicts. Reverted.)

#define NUM_USERS 100000
#define NUM_ITEMS 50000
#define N_NODES   150000
#define DIM       64
#define N_EDGES   1200000
#define ND        (N_NODES * DIM)
#define NB        4096
#define NSAMP     (2 * NB)

#define ELL_W     24
#define NBKT      640               // buckets
#define RPB       235               // rows per bucket (640*235 = 150400)
#define NROWS_PAD (NBKT * RPB)
#define BCAP      2176              // records per bucket array (mean 1875, +7s)
#define SCAP      9                 // LDS staging records per bucket (48.6KB)
#define OVF_CAP   512

#define K1_EDGE_BLOCKS 256
#define K1_ROUNDS      5            // ceil(1.2M / (256 blocks * 1024 edges))
#define K1_MARK_BLOCKS 32
#define K1_CVT_BLOCKS  512
#define K2_EXP_BLOCKS  2048
#define K2_CPY_BLOCKS  586
#define SPMM_BLOCKS    9375         // 16 rows/block
#define ACC_BLOCKS     512          // 16 slots/block

// ---- fp16 pack/unpack helpers (compute in fp32) ---------------------------
__device__ __forceinline__ int h2i(__half2 h) { int r; memcpy(&r, &h, 4); return r; }
__device__ __forceinline__ __half2 i2h(int i) { __half2 h; memcpy(&h, &i, 4); return h; }

__device__ __forceinline__ float4 loadh4(const __half* p) {
    int2 v = *(const int2*)p;
    float2 a = __half22float2(i2h(v.x));
    float2 b = __half22float2(i2h(v.y));
    return make_float4(a.x, a.y, b.x, b.y);
}
__device__ __forceinline__ void storeh4(__half* p, float4 v) {
    int2 o;
    o.x = h2i(__floats2half2_rn(v.x, v.y));
    o.y = h2i(__floats2half2_rn(v.z, v.w));
    *(int2*)p = o;
}
__device__ __forceinline__ float4 f4fma(float v, float4 x, float4 a) {
    a.x += v * x.x; a.y += v * x.y; a.z += v * x.z; a.w += v * x.w;
    return a;
}

// ---------------------------------------------------------------------------
// K1: LDS-staged counting sort (full-line flushes) + mark + cvt ride-along
// ---------------------------------------------------------------------------
__global__ __launch_bounds__(256)
void k1_kernel(const int* __restrict__ erow,
               const int* __restrict__ ecol,
               const float* __restrict__ evalv,
               const int* __restrict__ users,
               const int* __restrict__ items,
               const float* __restrict__ ue,
               const float* __restrict__ ie,
               int* __restrict__ gtails,
               int2* __restrict__ barr,
               int4* __restrict__ ovf,
               int* __restrict__ ovf_cnt,
               unsigned char* __restrict__ mask3,
               __half* __restrict__ xh) {
    __shared__ int2 stage[NBKT * SCAP];   // 46.1 KB
    __shared__ int  scnt[NBKT];           // 2.5 KB  -> 48.6 KB, 3 blocks/CU
    if (blockIdx.x < K1_EDGE_BLOCKS) {
        for (int k = threadIdx.x; k < NBKT; k += 256) scnt[k] = 0;
        __syncthreads();
        for (int rnd = 0; rnd < K1_ROUNDS; ++rnd) {
            int base = ((rnd * K1_EDGE_BLOCKS + (int)blockIdx.x) * 256
                        + (int)threadIdx.x) * 4;
            if (base < N_EDGES) {
                int4   r4 = *(const int4*)(erow + base);
                int4   c4 = *(const int4*)(ecol + base);
                float4 v4 = *(const float4*)(evalv + base);
                int   rr[4] = {r4.x, r4.y, r4.z, r4.w};
                int   cc[4] = {c4.x, c4.y, c4.z, c4.w};
                float vv[4] = {v4.x, v4.y, v4.z, v4.w};
                #pragma unroll
                for (int u = 0; u < 4; ++u) {
                    int b    = rr[u] / RPB;
                    int rloc = rr[u] - b * RPB;
                    int2 rec = make_int2(cc[u] | (rloc << 18), __float_as_int(vv[u]));
                    int s = atomicAdd(&scnt[b], 1);
                    if (s < SCAP) {
                        stage[b * SCAP + s] = rec;
                    } else {
                        atomicSub(&scnt[b], 1);
                        int gp = atomicAdd(&gtails[b], 1);
                        if (gp < BCAP) barr[(size_t)b * BCAP + gp] = rec;
                        else { int q = atomicAdd(ovf_cnt, 1);
                               if (q < OVF_CAP)
                                   ovf[q] = make_int4(rr[u], cc[u], __float_as_int(vv[u]), 0); }
                    }
                }
            }
            __syncthreads();
            for (int b = threadIdx.x; b < NBKT; b += 256) {
                int c = scnt[b];
                if (c >= 8) {
                    int gp = atomicAdd(&gtails[b], 8);
                    if (gp + 8 <= BCAP) {
                        int2* dst = barr + (size_t)b * BCAP + gp;
                        #pragma unroll
                        for (int i = 0; i < 8; ++i) dst[i] = stage[b * SCAP + i];
                    } else {
                        for (int i = 0; i < 8; ++i) {
                            int2 rc = stage[b * SCAP + i];
                            if (gp + i < BCAP) barr[(size_t)b * BCAP + gp + i] = rc;
                            else { int q = atomicAdd(ovf_cnt, 1);
                                   if (q < OVF_CAP)
                                       ovf[q] = make_int4(b * RPB + (rc.x >> 18),
                                                          rc.x & 0x3FFFF, rc.y, 0); }
                        }
                    }
                    c -= 8;
                    for (int i = 0; i < c; ++i)
                        stage[b * SCAP + i] = stage[b * SCAP + 8 + i];
                    scnt[b] = c;
                }
            }
            __syncthreads();
        }
        for (int b = threadIdx.x; b < NBKT; b += 256) {
            int c = scnt[b];
            if (c > 0) {
                int gp = atomicAdd(&gtails[b], c);
                for (int i = 0; i < c; ++i) {
                    int2 rc = stage[b * SCAP + i];
                    if (gp + i < BCAP) barr[(size_t)b * BCAP + gp + i] = rc;
                    else { int q = atomicAdd(ovf_cnt, 1);
                           if (q < OVF_CAP)
                               ovf[q] = make_int4(b * RPB + (rc.x >> 18),
                                                  rc.x & 0x3FFFF, rc.y, 0); }
                }
            }
        }
    } else if (blockIdx.x < K1_EDGE_BLOCKS + K1_MARK_BLOCKS) {
        int i = ((int)blockIdx.x - K1_EDGE_BLOCKS) * 256 + (int)threadIdx.x;
        if (i < NB)         mask3[users[i]] = 1;
        else if (i < NSAMP) mask3[NUM_USERS + items[i - NB]] = 1;
    } else {
        // cvt: concat(ue, ie) fp32 -> xh fp16 (fills free CU slots)
        const int n4  = ND / 4;
        const int nu4 = NUM_USERS * DIM / 4;
        int i = ((int)blockIdx.x - K1_EDGE_BLOCKS - K1_MARK_BLOCKS) * 256
                + (int)threadIdx.x;
        const int stride = K1_CVT_BLOCKS * 256;
        int2* xh4 = (int2*)xh;
        for (; i < n4; i += stride) {
            float4 v = (i < nu4) ? ((const float4*)ue)[i]
                                 : ((const float4*)ie)[i - nu4];
            int2 o;
            o.x = h2i(__floats2half2_rn(v.x, v.y));
            o.y = h2i(__floats2half2_rn(v.z, v.w));
            xh4[i] = o;
        }
    }
}

// ---------------------------------------------------------------------------
// K2: per-bucket ELL build in LDS + mask expand/copy
// ---------------------------------------------------------------------------
__global__ __launch_bounds__(256)
void k2_kernel(const int* __restrict__ erow,
               const int* __restrict__ ecol,
               const int* __restrict__ gtails,
               const int2* __restrict__ barr,
               int* __restrict__ counts,
               int2* __restrict__ ell,
               int4* __restrict__ ovf,
               int* __restrict__ ovf_cnt,
               const unsigned char* __restrict__ mask3,
               unsigned char* __restrict__ mask2) {
    __shared__ __align__(16) int2 lell[RPB * ELL_W];   // 45.1 KB
    __shared__ int lcnt[RPB];
    if (blockIdx.x < NBKT) {
        const int bkt   = blockIdx.x;
        const int rbase = bkt * RPB;
        for (int k = threadIdx.x; k < RPB; k += 256) lcnt[k] = 0;
        __syncthreads();
        int n = gtails[bkt];
        n = n < BCAP ? n : BCAP;
        for (int e = threadIdx.x; e < n; e += 256) {
            int2 rec = barr[(size_t)bkt * BCAP + e];
            int col  = rec.x & 0x3FFFF;
            int rloc = rec.x >> 18;
            int slot = atomicAdd(&lcnt[rloc], 1);
            if (slot < ELL_W)
                lell[rloc * ELL_W + slot] = make_int2(col, rec.y);
            else { int q = atomicAdd(ovf_cnt, 1);
                   if (q < OVF_CAP) ovf[q] = make_int4(rbase + rloc, col, rec.y, 0); }
        }
        __syncthreads();
        int4* g4 = (int4*)(ell + (size_t)rbase * ELL_W);
        const int4* l4 = (const int4*)lell;
        for (int k = threadIdx.x; k < RPB * ELL_W / 2; k += 256) g4[k] = l4[k];
        for (int k = threadIdx.x; k < RPB; k += 256) counts[rbase + k] = lcnt[k];
    } else if (blockIdx.x < NBKT + K2_EXP_BLOCKS) {
        int i = ((int)blockIdx.x - NBKT) * 256 + (int)threadIdx.x;
        const int stride = K2_EXP_BLOCKS * 256;
        for (; i < N_EDGES; i += stride)
            if (mask3[erow[i]]) mask2[ecol[i]] = 1;
    } else {
        int i = ((int)blockIdx.x - NBKT - K2_EXP_BLOCKS) * 256 + (int)threadIdx.x;
        if (i < N_NODES && mask3[i]) mask2[i] = 1;
    }
}

// ---------------------------------------------------------------------------
// fused spmm + blend (fp16 storage, fp32 math) + accum of the INPUT layer
// ---------------------------------------------------------------------------
template<bool MASKED, bool ACC_STORE>
__global__ void spmm_kernel(const int* __restrict__ counts,
                            const int2* __restrict__ ell,
                            const __half* __restrict__ xsrc,
                            const float* __restrict__ ue,
                            const float* __restrict__ ie,
                            const unsigned char* __restrict__ mask,
                            const int* __restrict__ ovf_cnt,
                            const int4* __restrict__ ovf,
                            const int* __restrict__ users,
                            const int* __restrict__ items,
                            float* __restrict__ acc_small,
                            __half* __restrict__ xout) {
    const int wid  = threadIdx.x >> 6;
    const int lane = threadIdx.x & 63;
    const int g    = lane >> 4;
    const int t    = lane & 15;

    if (blockIdx.x < SPMM_BLOCKS) {
        const int row = blockIdx.x * 16 + wid * 4 + g;
        bool active = true;
        if (MASKED) active = mask[row] != 0;
        int cnt = 0;
        if (active) {
            cnt = counts[row];
            cnt = cnt < ELL_W ? cnt : ELL_W;
        }
        const int2* ep = ell + (size_t)row * ELL_W;
        float4 a0 = {0,0,0,0}, a1 = {0,0,0,0}, a2 = {0,0,0,0}, a3 = {0,0,0,0};
        int j = 0;
        for (; j + 4 <= cnt; j += 4) {
            int4 cv0 = *(const int4*)(ep + j);
            int4 cv1 = *(const int4*)(ep + j + 2);
            float4 x0 = loadh4(xsrc + (size_t)cv0.x * DIM + t * 4);
            float4 x1 = loadh4(xsrc + (size_t)cv0.z * DIM + t * 4);
            float4 x2 = loadh4(xsrc + (size_t)cv1.x * DIM + t * 4);
            float4 x3 = loadh4(xsrc + (size_t)cv1.z * DIM + t * 4);
            a0 = f4fma(__int_as_float(cv0.y), x0, a0);
            a1 = f4fma(__int_as_float(cv0.w), x1, a1);
            a2 = f4fma(__int_as_float(cv1.y), x2, a2);
            a3 = f4fma(__int_as_float(cv1.w), x3, a3);
        }
        for (; j + 2 <= cnt; j += 2) {
            int4 cv = *(const int4*)(ep + j);
            float4 x0 = loadh4(xsrc + (size_t)cv.x * DIM + t * 4);
            float4 x1 = loadh4(xsrc + (size_t)cv.z * DIM + t * 4);
            a0 = f4fma(__int_as_float(cv.y), x0, a0);
            a1 = f4fma(__int_as_float(cv.w), x1, a1);
        }
        if (j < cnt) {
            int2 cv = ep[j];
            float4 xv = loadh4(xsrc + (size_t)cv.x * DIM + t * 4);
            a0 = f4fma(__int_as_float(cv.y), xv, a0);
        }
        int novf = *ovf_cnt;
        if (novf > 0) {
            novf = novf < OVF_CAP ? novf : OVF_CAP;
            for (int k = 0; k < novf; ++k) {
                int4 o = ovf[k];
                if (active && o.x == row) {
                    float4 xv = loadh4(xsrc + (size_t)o.y * DIM + t * 4);
                    a0 = f4fma(__int_as_float(o.z), xv, a0);
                }
            }
        }
        if (active) {
            float4 self = loadh4(xsrc + (size_t)row * DIM + t * 4);
            float4 r;
            r.x = 0.2f * self.x + 0.8f * ((a0.x + a1.x) + (a2.x + a3.x));
            r.y = 0.2f * self.y + 0.8f * ((a0.y + a1.y) + (a2.y + a3.y));
            r.z = 0.2f * self.z + 0.8f * ((a0.z + a1.z) + (a2.z + a3.z));
            r.w = 0.2f * self.w + 0.8f * ((a0.w + a1.w) + (a2.w + a3.w));
            storeh4(xout + (size_t)row * DIM + t * 4, r);
        }
    } else {
        const int s = (blockIdx.x - SPMM_BLOCKS) * 16 + wid * 4 + g;
        const int node = (s < NB) ? users[s] : (NUM_USERS + items[s - NB]);
        float4* ap = (float4*)(acc_small + (size_t)s * DIM + t * 4);
        if (ACC_STORE) {
            const float* p = (node < NUM_USERS) ? ue + (size_t)node * DIM
                                                : ie + (size_t)(node - NUM_USERS) * DIM;
            *ap = *(const float4*)(p + t * 4);
        } else {
            float4 v = loadh4(xsrc + (size_t)node * DIM + t * 4);
            float4 a = *ap;
            a.x += v.x; a.y += v.y; a.z += v.z; a.w += v.w;
            *ap = a;
        }
    }
}

// ---------------------------------------------------------------------------
__global__ void dot_kernel(const int* __restrict__ users,
                           const int* __restrict__ items,
                           const float* __restrict__ acc_small,
                           const __half* __restrict__ emb3,
                           float* __restrict__ out) {
    int w = (blockIdx.x * blockDim.x + threadIdx.x) >> 6;
    int lane = threadIdx.x & 63;
    if (w >= NB) return;
    int u  = users[w];
    int it = items[w];
    float au = acc_small[w * DIM + lane]
             + __half2float(emb3[(size_t)u * DIM + lane]);
    float ai = acc_small[(NB + w) * DIM + lane]
             + __half2float(emb3[(size_t)(NUM_USERS + it) * DIM + lane]);
    float p = au * ai;
    #pragma unroll
    for (int o = 32; o > 0; o >>= 1) p += __shfl_down(p, o, 64);
    if (lane == 0) out[w] = p * (1.0f / 16.0f);
}

// ---------------------------------------------------------------------------
extern "C" void kernel_launch(void* const* d_in, const int* in_sizes, int n_in,
                              void* d_out, int out_size, void* d_ws, size_t ws_size,
                              hipStream_t stream) {
    const int*   users = (const int*)  d_in[0];
    const int*   items = (const int*)  d_in[1];
    const int*   erow  = (const int*)  d_in[2];
    const int*   ecol  = (const int*)  d_in[3];
    const float* evalv = (const float*)d_in[4];
    const float* ue    = (const float*)d_in[5];
    const float* ie    = (const float*)d_in[6];
    float* out = (float*)d_out;

    // workspace layout (~90 MB)
    __half* xh        = (__half*)d_ws;                      // ND halves (19.2MB)
    __half* emb_a     = xh + ND;                            // ND halves
    __half* emb_b     = emb_a + ND;                         // ND halves
    int2*   barr      = (int2*)emb_a;                       // alias: 11.1MB <= 19.2MB
    float*  acc_small = (float*)(emb_b + ND);               // NSAMP*DIM fp32
    int2*   ell       = (int2*)(acc_small + NSAMP * DIM);   // NROWS_PAD*ELL_W int2
    int*    counts    = (int*)(ell + (size_t)NROWS_PAD * ELL_W); // NROWS_PAD
    int*    gtails    = counts + NROWS_PAD;                 // NBKT
    int*    ovf_cnt   = gtails + NBKT;                      // 1
    int4*   ovf       = (int4*)(((uintptr_t)(ovf_cnt + 1) + 15) & ~(uintptr_t)15);
    unsigned char* mask3 = (unsigned char*)(ovf + OVF_CAP); // N_NODES
    unsigned char* mask2 = mask3 + N_NODES;                 // N_NODES

    const int block = 256;

    // zero gtails | ovf_cnt | ovf | mask3 | mask2 (contiguous, ~310 KB)
    size_t zbytes = (size_t)((mask2 + N_NODES) - (unsigned char*)gtails);
    hipMemsetAsync(gtails, 0, zbytes, stream);

    k1_kernel<<<K1_EDGE_BLOCKS + K1_MARK_BLOCKS + K1_CVT_BLOCKS, block, 0, stream>>>(
        erow, ecol, evalv, users, items, ue, ie,
        gtails, barr, ovf, ovf_cnt, mask3, xh);

    k2_kernel<<<NBKT + K2_EXP_BLOCKS + K2_CPY_BLOCKS, block, 0, stream>>>(
        erow, ecol, gtails, barr, counts, ell, ovf, ovf_cnt, mask3, mask2);

    // layer 1 (unmasked, gathers xh) + acc0(store from fp32 tables)
    spmm_kernel<false, true><<<SPMM_BLOCKS + ACC_BLOCKS, block, 0, stream>>>(
        counts, ell, xh, ue, ie, nullptr, ovf_cnt, ovf,
        users, items, acc_small, emb_a);

    // layer 2 (mask2) + acc1 (from emb_a)
    spmm_kernel<true, false><<<SPMM_BLOCKS + ACC_BLOCKS, block, 0, stream>>>(
        counts, ell, emb_a, nullptr, nullptr, mask2, ovf_cnt, ovf,
        users, items, acc_small, emb_b);

    // layer 3 (mask3) + acc2 (from emb_b)
    spmm_kernel<true, false><<<SPMM_BLOCKS + ACC_BLOCKS, block, 0, stream>>>(
        counts, ell, emb_b, nullptr, nullptr, mask3, ovf_cnt, ovf,
        users, items, acc_small, emb_a);

    // dot with layer-3 accum fused
    dot_kernel<<<(NB * 64 + 255) / 256, block, 0, stream>>>(
        users, items, acc_small, emb_a, out);
}

// Round 11
// 209.107 us; speedup vs baseline: 4.1966x; 1.0238x over previous
//
#include <hip/hip_runtime.h>
#include <hip/hip_fp16.h>
#include <stdint.h>
#include <string.h>

// LightGCN propagation — R8/R10 structure with wide (1024-thread) K1.
//  K1: 256 edge blocks x 1024 threads (16 waves — R10's 4-wave version was
//      latency-bound at 16% occupancy), LDS staging SCAP=11 (58.9KB), 2
//      rounds of int4 edge reads, full-line flushes; staging overflow (~2%)
//      falls back to direct global append. Mark + cvt ride along.
//  K2: per-bucket ELL build in LDS (coalesced writeout) + mask expand/copy.
//  spmm x3: ELL per-row register accumulation, fp16 gathers, 4 rows/wave,
//      4-edge unroll, fused accum of the input layer.
//  dot: fused layer-3 accum + batched dot.

#define NUM_USERS 100000
#define NUM_ITEMS 50000
#define N_NODES   150000
#define DIM       64
#define N_EDGES   1200000
#define ND        (N_NODES * DIM)
#define NB        4096
#define NSAMP     (2 * NB)

#define ELL_W     24
#define NBKT      640               // buckets
#define RPB       235               // rows per bucket (640*235 = 150400)
#define NROWS_PAD (NBKT * RPB)
#define BCAP      2176              // records per bucket array (mean 1875, +7s)
#define SCAP      11                // LDS staging records per bucket (58.9KB)
#define OVF_CAP   512

#define K1_THREADS     1024
#define K1_EDGE_BLOCKS 256
#define K1_ROUNDS      2            // ceil(1.2M / (256 * 1024 * 4))
#define K1_MARK_BLOCKS 8            // 8*1024 = 8192 = NSAMP
#define K1_CVT_BLOCKS  128
#define K2_EXP_BLOCKS  2048
#define K2_CPY_BLOCKS  586
#define SPMM_BLOCKS    9375         // 16 rows/block
#define ACC_BLOCKS     512          // 16 slots/block

// ---- fp16 pack/unpack helpers (compute in fp32) ---------------------------
__device__ __forceinline__ int h2i(__half2 h) { int r; memcpy(&r, &h, 4); return r; }
__device__ __forceinline__ __half2 i2h(int i) { __half2 h; memcpy(&h, &i, 4); return h; }

__device__ __forceinline__ float4 loadh4(const __half* p) {
    int2 v = *(const int2*)p;
    float2 a = __half22float2(i2h(v.x));
    float2 b = __half22float2(i2h(v.y));
    return make_float4(a.x, a.y, b.x, b.y);
}
__device__ __forceinline__ void storeh4(__half* p, float4 v) {
    int2 o;
    o.x = h2i(__floats2half2_rn(v.x, v.y));
    o.y = h2i(__floats2half2_rn(v.z, v.w));
    *(int2*)p = o;
}
__device__ __forceinline__ float4 f4fma(float v, float4 x, float4 a) {
    a.x += v * x.x; a.y += v * x.y; a.z += v * x.z; a.w += v * x.w;
    return a;
}

// ---------------------------------------------------------------------------
// K1: LDS-staged counting sort (wide blocks) + mark + cvt ride-along
// ---------------------------------------------------------------------------
__global__ __launch_bounds__(K1_THREADS)
void k1_kernel(const int* __restrict__ erow,
               const int* __restrict__ ecol,
               const float* __restrict__ evalv,
               const int* __restrict__ users,
               const int* __restrict__ items,
               const float* __restrict__ ue,
               const float* __restrict__ ie,
               int* __restrict__ gtails,
               int2* __restrict__ barr,
               int4* __restrict__ ovf,
               int* __restrict__ ovf_cnt,
               unsigned char* __restrict__ mask3,
               __half* __restrict__ xh) {
    __shared__ int2 stage[NBKT * SCAP];   // 56.3 KB
    __shared__ int  scnt[NBKT];           // 2.5 KB  -> 58.9 KB total
    if (blockIdx.x < K1_EDGE_BLOCKS) {
        for (int k = threadIdx.x; k < NBKT; k += K1_THREADS) scnt[k] = 0;
        __syncthreads();
        for (int rnd = 0; rnd < K1_ROUNDS; ++rnd) {
            int base = ((rnd * K1_EDGE_BLOCKS + (int)blockIdx.x) * K1_THREADS
                        + (int)threadIdx.x) * 4;
            if (base < N_EDGES) {
                int4   r4 = *(const int4*)(erow + base);
                int4   c4 = *(const int4*)(ecol + base);
                float4 v4 = *(const float4*)(evalv + base);
                int   rr[4] = {r4.x, r4.y, r4.z, r4.w};
                int   cc[4] = {c4.x, c4.y, c4.z, c4.w};
                float vv[4] = {v4.x, v4.y, v4.z, v4.w};
                #pragma unroll
                for (int u = 0; u < 4; ++u) {
                    int b    = rr[u] / RPB;
                    int rloc = rr[u] - b * RPB;
                    int2 rec = make_int2(cc[u] | (rloc << 18), __float_as_int(vv[u]));
                    int s = atomicAdd(&scnt[b], 1);
                    if (s < SCAP) {
                        stage[b * SCAP + s] = rec;
                    } else {
                        atomicSub(&scnt[b], 1);
                        int gp = atomicAdd(&gtails[b], 1);
                        if (gp < BCAP) barr[(size_t)b * BCAP + gp] = rec;
                        else { int q = atomicAdd(ovf_cnt, 1);
                               if (q < OVF_CAP)
                                   ovf[q] = make_int4(rr[u], cc[u], __float_as_int(vv[u]), 0); }
                    }
                }
            }
            __syncthreads();
            // flush one full 64-B line per bucket with >= 8 staged
            for (int b = threadIdx.x; b < NBKT; b += K1_THREADS) {
                int c = scnt[b];
                if (c >= 8) {
                    int gp = atomicAdd(&gtails[b], 8);
                    if (gp + 8 <= BCAP) {
                        int2* dst = barr + (size_t)b * BCAP + gp;
                        #pragma unroll
                        for (int i = 0; i < 8; ++i) dst[i] = stage[b * SCAP + i];
                    } else {
                        for (int i = 0; i < 8; ++i) {
                            int2 rc = stage[b * SCAP + i];
                            if (gp + i < BCAP) barr[(size_t)b * BCAP + gp + i] = rc;
                            else { int q = atomicAdd(ovf_cnt, 1);
                                   if (q < OVF_CAP)
                                       ovf[q] = make_int4(b * RPB + (rc.x >> 18),
                                                          rc.x & 0x3FFFF, rc.y, 0); }
                        }
                    }
                    c -= 8;
                    for (int i = 0; i < c; ++i)
                        stage[b * SCAP + i] = stage[b * SCAP + 8 + i];
                    scnt[b] = c;
                }
            }
            __syncthreads();
        }
        // final flush of remainders (contiguous short runs; pack in L2)
        for (int b = threadIdx.x; b < NBKT; b += K1_THREADS) {
            int c = scnt[b];
            if (c > 0) {
                int gp = atomicAdd(&gtails[b], c);
                for (int i = 0; i < c; ++i) {
                    int2 rc = stage[b * SCAP + i];
                    if (gp + i < BCAP) barr[(size_t)b * BCAP + gp + i] = rc;
                    else { int q = atomicAdd(ovf_cnt, 1);
                           if (q < OVF_CAP)
                               ovf[q] = make_int4(b * RPB + (rc.x >> 18),
                                                  rc.x & 0x3FFFF, rc.y, 0); }
                }
            }
        }
    } else if (blockIdx.x < K1_EDGE_BLOCKS + K1_MARK_BLOCKS) {
        int i = ((int)blockIdx.x - K1_EDGE_BLOCKS) * K1_THREADS + (int)threadIdx.x;
        if (i < NB)         mask3[users[i]] = 1;
        else if (i < NSAMP) mask3[NUM_USERS + items[i - NB]] = 1;
    } else {
        // cvt: concat(ue, ie) fp32 -> xh fp16
        const int n4  = ND / 4;
        const int nu4 = NUM_USERS * DIM / 4;
        int i = ((int)blockIdx.x - K1_EDGE_BLOCKS - K1_MARK_BLOCKS) * K1_THREADS
                + (int)threadIdx.x;
        const int stride = K1_CVT_BLOCKS * K1_THREADS;
        int2* xh4 = (int2*)xh;
        for (; i < n4; i += stride) {
            float4 v = (i < nu4) ? ((const float4*)ue)[i]
                                 : ((const float4*)ie)[i - nu4];
            int2 o;
            o.x = h2i(__floats2half2_rn(v.x, v.y));
            o.y = h2i(__floats2half2_rn(v.z, v.w));
            xh4[i] = o;
        }
    }
}

// ---------------------------------------------------------------------------
// K2: per-bucket ELL build in LDS + mask expand/copy
// ---------------------------------------------------------------------------
__global__ __launch_bounds__(256)
void k2_kernel(const int* __restrict__ erow,
               const int* __restrict__ ecol,
               const int* __restrict__ gtails,
               const int2* __restrict__ barr,
               int* __restrict__ counts,
               int2* __restrict__ ell,
               int4* __restrict__ ovf,
               int* __restrict__ ovf_cnt,
               const unsigned char* __restrict__ mask3,
               unsigned char* __restrict__ mask2) {
    __shared__ __align__(16) int2 lell[RPB * ELL_W];   // 45.1 KB
    __shared__ int lcnt[RPB];
    if (blockIdx.x < NBKT) {
        const int bkt   = blockIdx.x;
        const int rbase = bkt * RPB;
        for (int k = threadIdx.x; k < RPB; k += 256) lcnt[k] = 0;
        __syncthreads();
        int n = gtails[bkt];
        n = n < BCAP ? n : BCAP;
        for (int e = threadIdx.x; e < n; e += 256) {
            int2 rec = barr[(size_t)bkt * BCAP + e];
            int col  = rec.x & 0x3FFFF;
            int rloc = rec.x >> 18;
            int slot = atomicAdd(&lcnt[rloc], 1);
            if (slot < ELL_W)
                lell[rloc * ELL_W + slot] = make_int2(col, rec.y);
            else { int q = atomicAdd(ovf_cnt, 1);
                   if (q < OVF_CAP) ovf[q] = make_int4(rbase + rloc, col, rec.y, 0); }
        }
        __syncthreads();
        int4* g4 = (int4*)(ell + (size_t)rbase * ELL_W);
        const int4* l4 = (const int4*)lell;
        for (int k = threadIdx.x; k < RPB * ELL_W / 2; k += 256) g4[k] = l4[k];
        for (int k = threadIdx.x; k < RPB; k += 256) counts[rbase + k] = lcnt[k];
    } else if (blockIdx.x < NBKT + K2_EXP_BLOCKS) {
        int i = ((int)blockIdx.x - NBKT) * 256 + (int)threadIdx.x;
        const int stride = K2_EXP_BLOCKS * 256;
        for (; i < N_EDGES; i += stride)
            if (mask3[erow[i]]) mask2[ecol[i]] = 1;
    } else {
        int i = ((int)blockIdx.x - NBKT - K2_EXP_BLOCKS) * 256 + (int)threadIdx.x;
        if (i < N_NODES && mask3[i]) mask2[i] = 1;
    }
}

// ---------------------------------------------------------------------------
// fused spmm + blend (fp16 storage, fp32 math) + accum of the INPUT layer
// ---------------------------------------------------------------------------
template<bool MASKED, bool ACC_STORE>
__global__ void spmm_kernel(const int* __restrict__ counts,
                            const int2* __restrict__ ell,
                            const __half* __restrict__ xsrc,
                            const float* __restrict__ ue,
                            const float* __restrict__ ie,
                            const unsigned char* __restrict__ mask,
                            const int* __restrict__ ovf_cnt,
                            const int4* __restrict__ ovf,
                            const int* __restrict__ users,
                            const int* __restrict__ items,
                            float* __restrict__ acc_small,
                            __half* __restrict__ xout) {
    const int wid  = threadIdx.x >> 6;
    const int lane = threadIdx.x & 63;
    const int g    = lane >> 4;
    const int t    = lane & 15;

    if (blockIdx.x < SPMM_BLOCKS) {
        const int row = blockIdx.x * 16 + wid * 4 + g;
        bool active = true;
        if (MASKED) active = mask[row] != 0;
        int cnt = 0;
        if (active) {
            cnt = counts[row];
            cnt = cnt < ELL_W ? cnt : ELL_W;
        }
        const int2* ep = ell + (size_t)row * ELL_W;
        float4 a0 = {0,0,0,0}, a1 = {0,0,0,0}, a2 = {0,0,0,0}, a3 = {0,0,0,0};
        int j = 0;
        for (; j + 4 <= cnt; j += 4) {
            int4 cv0 = *(const int4*)(ep + j);
            int4 cv1 = *(const int4*)(ep + j + 2);
            float4 x0 = loadh4(xsrc + (size_t)cv0.x * DIM + t * 4);
            float4 x1 = loadh4(xsrc + (size_t)cv0.z * DIM + t * 4);
            float4 x2 = loadh4(xsrc + (size_t)cv1.x * DIM + t * 4);
            float4 x3 = loadh4(xsrc + (size_t)cv1.z * DIM + t * 4);
            a0 = f4fma(__int_as_float(cv0.y), x0, a0);
            a1 = f4fma(__int_as_float(cv0.w), x1, a1);
            a2 = f4fma(__int_as_float(cv1.y), x2, a2);
            a3 = f4fma(__int_as_float(cv1.w), x3, a3);
        }
        for (; j + 2 <= cnt; j += 2) {
            int4 cv = *(const int4*)(ep + j);
            float4 x0 = loadh4(xsrc + (size_t)cv.x * DIM + t * 4);
            float4 x1 = loadh4(xsrc + (size_t)cv.z * DIM + t * 4);
            a0 = f4fma(__int_as_float(cv.y), x0, a0);
            a1 = f4fma(__int_as_float(cv.w), x1, a1);
        }
        if (j < cnt) {
            int2 cv = ep[j];
            float4 xv = loadh4(xsrc + (size_t)cv.x * DIM + t * 4);
            a0 = f4fma(__int_as_float(cv.y), xv, a0);
        }
        int novf = *ovf_cnt;
        if (novf > 0) {
            novf = novf < OVF_CAP ? novf : OVF_CAP;
            for (int k = 0; k < novf; ++k) {
                int4 o = ovf[k];
                if (active && o.x == row) {
                    float4 xv = loadh4(xsrc + (size_t)o.y * DIM + t * 4);
                    a0 = f4fma(__int_as_float(o.z), xv, a0);
                }
            }
        }
        if (active) {
            float4 self = loadh4(xsrc + (size_t)row * DIM + t * 4);
            float4 r;
            r.x = 0.2f * self.x + 0.8f * ((a0.x + a1.x) + (a2.x + a3.x));
            r.y = 0.2f * self.y + 0.8f * ((a0.y + a1.y) + (a2.y + a3.y));
            r.z = 0.2f * self.z + 0.8f * ((a0.z + a1.z) + (a2.z + a3.z));
            r.w = 0.2f * self.w + 0.8f * ((a0.w + a1.w) + (a2.w + a3.w));
            storeh4(xout + (size_t)row * DIM + t * 4, r);
        }
    } else {
        const int s = (blockIdx.x - SPMM_BLOCKS) * 16 + wid * 4 + g;
        const int node = (s < NB) ? users[s] : (NUM_USERS + items[s - NB]);
        float4* ap = (float4*)(acc_small + (size_t)s * DIM + t * 4);
        if (ACC_STORE) {
            const float* p = (node < NUM_USERS) ? ue + (size_t)node * DIM
                                                : ie + (size_t)(node - NUM_USERS) * DIM;
            *ap = *(const float4*)(p + t * 4);
        } else {
            float4 v = loadh4(xsrc + (size_t)node * DIM + t * 4);
            float4 a = *ap;
            a.x += v.x; a.y += v.y; a.z += v.z; a.w += v.w;
            *ap = a;
        }
    }
}

// ---------------------------------------------------------------------------
__global__ void dot_kernel(const int* __restrict__ users,
                           const int* __restrict__ items,
                           const float* __restrict__ acc_small,
                           const __half* __restrict__ emb3,
                           float* __restrict__ out) {
    int w = (blockIdx.x * blockDim.x + threadIdx.x) >> 6;
    int lane = threadIdx.x & 63;
    if (w >= NB) return;
    int u  = users[w];
    int it = items[w];
    float au = acc_small[w * DIM + lane]
             + __half2float(emb3[(size_t)u * DIM + lane]);
    float ai = acc_small[(NB + w) * DIM + lane]
             + __half2float(emb3[(size_t)(NUM_USERS + it) * DIM + lane]);
    float p = au * ai;
    #pragma unroll
    for (int o = 32; o > 0; o >>= 1) p += __shfl_down(p, o, 64);
    if (lane == 0) out[w] = p * (1.0f / 16.0f);
}

// ---------------------------------------------------------------------------
extern "C" void kernel_launch(void* const* d_in, const int* in_sizes, int n_in,
                              void* d_out, int out_size, void* d_ws, size_t ws_size,
                              hipStream_t stream) {
    const int*   users = (const int*)  d_in[0];
    const int*   items = (const int*)  d_in[1];
    const int*   erow  = (const int*)  d_in[2];
    const int*   ecol  = (const int*)  d_in[3];
    const float* evalv = (const float*)d_in[4];
    const float* ue    = (const float*)d_in[5];
    const float* ie    = (const float*)d_in[6];
    float* out = (float*)d_out;

    // workspace layout (~90 MB)
    __half* xh        = (__half*)d_ws;                      // ND halves (19.2MB)
    __half* emb_a     = xh + ND;                            // ND halves
    __half* emb_b     = emb_a + ND;                         // ND halves
    int2*   barr      = (int2*)emb_a;                       // alias: 11.1MB <= 19.2MB
    float*  acc_small = (float*)(emb_b + ND);               // NSAMP*DIM fp32
    int2*   ell       = (int2*)(acc_small + NSAMP * DIM);   // NROWS_PAD*ELL_W int2
    int*    counts    = (int*)(ell + (size_t)NROWS_PAD * ELL_W); // NROWS_PAD
    int*    gtails    = counts + NROWS_PAD;                 // NBKT
    int*    ovf_cnt   = gtails + NBKT;                      // 1
    int4*   ovf       = (int4*)(((uintptr_t)(ovf_cnt + 1) + 15) & ~(uintptr_t)15);
    unsigned char* mask3 = (unsigned char*)(ovf + OVF_CAP); // N_NODES
    unsigned char* mask2 = mask3 + N_NODES;                 // N_NODES

    // zero gtails | ovf_cnt | ovf | mask3 | mask2 (contiguous, ~310 KB)
    size_t zbytes = (size_t)((mask2 + N_NODES) - (unsigned char*)gtails);
    hipMemsetAsync(gtails, 0, zbytes, stream);

    k1_kernel<<<K1_EDGE_BLOCKS + K1_MARK_BLOCKS + K1_CVT_BLOCKS, K1_THREADS, 0, stream>>>(
        erow, ecol, evalv, users, items, ue, ie,
        gtails, barr, ovf, ovf_cnt, mask3, xh);

    k2_kernel<<<NBKT + K2_EXP_BLOCKS + K2_CPY_BLOCKS, 256, 0, stream>>>(
        erow, ecol, gtails, barr, counts, ell, ovf, ovf_cnt, mask3, mask2);

    // layer 1 (unmasked, gathers xh) + acc0(store from fp32 tables)
    spmm_kernel<false, true><<<SPMM_BLOCKS + ACC_BLOCKS, 256, 0, stream>>>(
        counts, ell, xh, ue, ie, nullptr, ovf_cnt, ovf,
        users, items, acc_small, emb_a);

    // layer 2 (mask2) + acc1 (from emb_a)
    spmm_kernel<true, false><<<SPMM_BLOCKS + ACC_BLOCKS, 256, 0, stream>>>(
        counts, ell, emb_a, nullptr, nullptr, mask2, ovf_cnt, ovf,
        users, items, acc_small, emb_b);

    // layer 3 (mask3) + acc2 (from emb_b)
    spmm_kernel<true, false><<<SPMM_BLOCKS + ACC_BLOCKS, 256, 0, stream>>>(
        counts, ell, emb_b, nullptr, nullptr, mask3, ovf_cnt, ovf,
        users, items, acc_small, emb_a);

    // dot with layer-3 accum fused
    dot_kernel<<<(NB * 64 + 255) / 256, 256, 0, stream>>>(
        users, items, acc_small, emb_a, out);
}